// Round 6
// baseline (580.300 us; speedup 1.0000x reference)
//
#include <hip/hip_runtime.h>
#include <hip/hip_bf16.h>
#include <math.h>

#define Dm   1024
#define Hh   16
#define Sx   2048

typedef short s16x8 __attribute__((ext_vector_type(8)));
typedef float f32x4 __attribute__((ext_vector_type(4)));
typedef unsigned short u16;
typedef u16 u16x4 __attribute__((ext_vector_type(4)));

#if defined(__has_builtin)
#  if __has_builtin(__builtin_amdgcn_cvt_pk_bf16_f32)
#    define HAVE_PKBF16 1
typedef __bf16 bfv2 __attribute__((ext_vector_type(2)));
#  endif
#  if __has_builtin(__builtin_amdgcn_exp2f)
#    define EXP2(x) __builtin_amdgcn_exp2f(x)
#  endif
#endif
#ifndef EXP2
#  define EXP2(x) exp2f(x)
#endif

// logit scale folded into k and p: dh^-0.5 * log2(e)
#define ATT_SCALE 0.1803368801111204f

__device__ __forceinline__ float wave_sum64(float v) {
#pragma unroll
    for (int o = 32; o > 0; o >>= 1) v += __shfl_xor(v, o, 64);
    return v;
}
__device__ __forceinline__ u16 f2bf(float x) {
    unsigned int u = __float_as_uint(x);
    unsigned int r = u + 0x7FFFu + ((u >> 16) & 1u);
    return (u16)(r >> 16);
}
__device__ __forceinline__ float bf2f(u16 h) {
    return __uint_as_float(((unsigned int)h) << 16);
}
__device__ __forceinline__ f32x4 mfma16(s16x8 a, s16x8 b, f32x4 c) {
    return __builtin_amdgcn_mfma_f32_16x16x32_bf16(a, b, c, 0, 0, 0);
}
// direct global->LDS DMA, 16B/lane; LDS dest = wave-uniform base + lane*16
__device__ __forceinline__ void gl16(const u16* gp, u16* lp) {
    __builtin_amdgcn_global_load_lds(
        (__attribute__((address_space(1))) void*)(gp),
        (__attribute__((address_space(3))) void*)(lp), 16, 0, 0);
}
__device__ __forceinline__ void pa_store(u16* PA, int i0_, int i1_, float e0v, float e1v) {
#ifdef HAVE_PKBF16
    bfv2 pk2 = __builtin_amdgcn_cvt_pk_bf16_f32(e0v, e1v);
    PA[i0_] = __builtin_bit_cast(u16, pk2[0]);
    PA[i1_] = __builtin_bit_cast(u16, pk2[1]);
#else
    PA[i0_] = f2bf(e0v);
    PA[i1_] = f2bf(e1v);
#endif
}

// ---------------------------------------------------------------- LayerNorm -> pre-split bf16 hi|lo
__global__ __launch_bounds__(256) void ln_kernel(const float* __restrict__ x,
                                                 const float* __restrict__ g,
                                                 const float* __restrict__ b,
                                                 u16* __restrict__ out16) {
    int row = blockIdx.x;
    int tid = threadIdx.x;
    const float4* xr = (const float4*)(x + (size_t)row * Dm);
    float4 v = xr[tid];
    float s  = v.x + v.y + v.z + v.w;
    float ss = v.x * v.x + v.y * v.y + v.z * v.z + v.w * v.w;
    __shared__ float rbuf[8];
    s  = wave_sum64(s);
    ss = wave_sum64(ss);
    if ((tid & 63) == 0) { rbuf[tid >> 6] = s; rbuf[4 + (tid >> 6)] = ss; }
    __syncthreads();
    float mean = (rbuf[0] + rbuf[1] + rbuf[2] + rbuf[3]) * (1.0f / Dm);
    float msq  = (rbuf[4] + rbuf[5] + rbuf[6] + rbuf[7]) * (1.0f / Dm);
    float var  = msq - mean * mean;
    float rstd = 1.0f / sqrtf(var + 1e-5f);
    float4 gg = ((const float4*)g)[tid];
    float4 bb = ((const float4*)b)[tid];
    float o[4];
    o[0] = (v.x - mean) * rstd * gg.x + bb.x;
    o[1] = (v.y - mean) * rstd * gg.y + bb.y;
    o[2] = (v.z - mean) * rstd * gg.z + bb.z;
    o[3] = (v.w - mean) * rstd * gg.w + bb.w;
    u16x4 hi, lo;
#pragma unroll
    for (int i = 0; i < 4; i++) {
        u16 h = f2bf(o[i]);
        hi[i] = h;
        lo[i] = f2bf(o[i] - bf2f(h));
    }
    *(u16x4*)&out16[(size_t)row * 2048 + tid * 4]        = hi;
    *(u16x4*)&out16[(size_t)row * 2048 + 1024 + tid * 4] = lo;
}

// ---------------------------------------------------------------- sinusoidal PE -> pre-split bf16
// fp32 transcendentals (double exp/sin/cos are software-emulated and VALU-heavy).
// fp32 path also matches the fp32 reference rounding of ang = r*div more closely.
__global__ __launch_bounds__(256) void pe_kernel(u16* __restrict__ pe16) {
    int idx = blockIdx.x * 256 + threadIdx.x;
    int r = idx >> 9;
    int t = idx & 511;
    float div = expf((float)(2 * t) * (-9.210340371976184f / 1024.0f));
    float ang = (float)r * div;
    float sv, cv;
    sincosf(ang, &sv, &cv);
    u16 sh = f2bf(sv), chh = f2bf(cv);
    u16* row = pe16 + (size_t)r * 2048;
    row[2 * t]            = sh;
    row[2 * t + 1]        = chh;
    row[1024 + 2 * t]     = f2bf(sv - bf2f(sh));
    row[1024 + 2 * t + 1] = f2bf(cv - bf2f(chh));
}

// ---------------------------------------------------------------- weight transpose + bf16 hi/lo split
__global__ __launch_bounds__(256) void wconv_kernel(const float* __restrict__ W0,
                                                    const float* __restrict__ W1,
                                                    const float* __restrict__ W2,
                                                    const float* __restrict__ W3,
                                                    const float* __restrict__ W4,
                                                    u16* __restrict__ WT) {
    int wz = blockIdx.z;
    const float* W = (wz == 0) ? W0 : (wz == 1) ? W1 : (wz == 2) ? W2 : (wz == 3) ? W3 : W4;
    u16* T = WT + (size_t)wz * 1024 * 2048;
    __shared__ float tile[32][33];
    int n0 = blockIdx.x * 32, k0 = blockIdx.y * 32;
    int tx = threadIdx.x & 31, ty = threadIdx.x >> 5;
#pragma unroll
    for (int r = 0; r < 32; r += 8)
        tile[ty + r][tx] = W[(size_t)(k0 + ty + r) * 1024 + n0 + tx];
    __syncthreads();
#pragma unroll
    for (int r = 0; r < 32; r += 8) {
        int n = ty + r;
        float x = tile[tx][n];
        u16 h = f2bf(x);
        float rem = x - bf2f(h);
        T[(size_t)(n0 + n) * 2048 + k0 + tx]        = h;
        T[(size_t)(n0 + n) * 2048 + 1024 + k0 + tx] = f2bf(rem);
    }
}

// ---------------------------------------------------------------- bf16x3 MFMA GEMM, global_load_lds staging
// (round-5, frozen) BMT x 128 tile, direct global->LDS DMA with both-sides XOR swizzle.
template<int BMT>
__global__ __launch_bounds__(256, 4) void gemm128k(const u16* __restrict__ A,
                                                   const u16* __restrict__ A2,
                                                   const u16* __restrict__ WT,
                                                   const float* __restrict__ b0,
                                                   const float* __restrict__ b1,
                                                   const float* __restrict__ b2,
                                                   u16* __restrict__ Cb,
                                                   float* __restrict__ C,
                                                   int mode) {
    constexpr int MT  = BMT / 32;
    constexpr int AC  = BMT / 32;
    constexpr int RPW = BMT / 4;
    __shared__ __align__(16) u16 AhL[BMT * 64];
    __shared__ __align__(16) u16 BhL[128 * 64];
    int tid = threadIdx.x;
    int gx, gy, widx;
    const u16* Asrc = A;
    if (mode == 0) {
        int bid = blockIdx.x;
        if (bid < 768) { gx = bid % 24; gy = bid / 24; widx = gx >> 3; gx &= 7; }
        else           { int r2 = bid - 768; gx = r2 & 7; gy = r2 >> 3; widx = 3; Asrc = A2; }
    } else {
        gx = blockIdx.x; gy = blockIdx.y; widx = 4;
    }
    int bn = gx * 128, bm = gy * BMT;
    const u16* Wb = WT + (size_t)widx * (1024 * 2048);
    const float* bias = (widx == 0) ? b0 : (widx == 1) ? b1 : (widx == 2) ? b2
                      : (widx == 4) ? b0 : nullptr;
    float csc = (widx == 1 || widx == 3) ? ATT_SCALE : 1.0f;

    int w = tid >> 6, ln = tid & 63, g = ln >> 4, l15 = ln & 15;
    int wm = (w & 1) * (BMT / 2), wn = (w >> 1) * 64;

    int key = ln >> 3;
    int cg  = (ln & 7) ^ key;
    int gcol = (cg < 4) ? cg * 8 : 1024 + (cg - 4) * 8;
    const u16* gA = Asrc + (size_t)(bm + w * RPW + key) * 2048 + gcol;
    const u16* gB = Wb   + (size_t)(bn + w * 32  + key) * 2048 + gcol;
    u16* lA = &AhL[(w * RPW) * 64];
    u16* lB = &BhL[(w * 32) * 64];

    int keyr = l15 & 7;
    int chH = (g ^ keyr) * 8;
    int chL = ((4 + g) ^ keyr) * 8;

    f32x4 acc[MT][4] = {};

    for (int k0 = 0; k0 < 1024; k0 += 32) {
#pragma unroll
        for (int c = 0; c < AC; c++)
            gl16(gA + c * (8 * 2048) + k0, lA + c * (8 * 64));
#pragma unroll
        for (int c = 0; c < 4; c++)
            gl16(gB + c * (8 * 2048) + k0, lB + c * (8 * 64));
        __syncthreads();

        s16x8 bhf[4], blf[4];
#pragma unroll
        for (int nt = 0; nt < 4; nt++) {
            int br = (wn + nt * 16 + l15) * 64;
            bhf[nt] = *(const s16x8*)&BhL[br + chH];
            blf[nt] = *(const s16x8*)&BhL[br + chL];
        }
#pragma unroll
        for (int mt = 0; mt < MT; mt++) {
            int ar = (wm + mt * 16 + l15) * 64;
            s16x8 ah = *(const s16x8*)&AhL[ar + chH];
            s16x8 al = *(const s16x8*)&AhL[ar + chL];
#pragma unroll
            for (int nt = 0; nt < 4; nt++) {
                acc[mt][nt] = mfma16(ah, bhf[nt], acc[mt][nt]);
                acc[mt][nt] = mfma16(al, bhf[nt], acc[mt][nt]);
                acc[mt][nt] = mfma16(ah, blf[nt], acc[mt][nt]);
            }
        }
        __syncthreads();
    }

    float bv4[4];
#pragma unroll
    for (int nt = 0; nt < 4; nt++)
        bv4[nt] = bias ? bias[bn + wn + nt * 16 + l15] : 0.0f;
    if (mode == 0) {
        u16* Co = Cb + (size_t)widx * (4096 * 1024);
#pragma unroll
        for (int mt = 0; mt < MT; mt++)
#pragma unroll
            for (int r = 0; r < 4; r++) {
                int row = bm + wm + mt * 16 + g * 4 + r;
                u16* cp = Co + (size_t)row * 1024 + bn + wn + l15;
#pragma unroll
                for (int nt = 0; nt < 4; nt++)
                    cp[16 * nt] = f2bf((acc[mt][nt][r] + bv4[nt]) * csc);
            }
    } else {
#pragma unroll
        for (int mt = 0; mt < MT; mt++)
#pragma unroll
            for (int r = 0; r < 4; r++) {
                int row = bm + wm + mt * 16 + g * 4 + r;
                float* cp = C + (size_t)row * 1024 + bn + wn + l15;
#pragma unroll
                for (int nt = 0; nt < 4; nt++)
                    cp[16 * nt] = acc[mt][nt][r] + bv4[nt];
            }
    }
}

// ---------------------------------------------------------------- V transpose to tiled [b][h][jt][d][32]
__global__ __launch_bounds__(256) void vtrans_kernel(const u16* __restrict__ v,
                                                     u16* __restrict__ vT) {
    __shared__ u16 L[32 * 72];
    int jt = blockIdx.x, h = blockIdx.y, b = blockIdx.z;
    int tid = threadIdx.x;
    int row = tid >> 3, cc = tid & 7;
    const u16* src = v + ((size_t)(b * Sx + jt * 32 + row)) * Dm + h * 64 + cc * 8;
    *(s16x8*)&L[row * 72 + cc * 8] = *(const s16x8*)src;
    __syncthreads();
    int d = tid >> 2, jq = tid & 3;
    s16x8 o;
#pragma unroll
    for (int jj = 0; jj < 8; jj++) o[jj] = (short)L[(jq * 8 + jj) * 72 + d];
    u16* dst = vT + (((size_t)(b * 16 + h) * 64 + jt)) * 2048 + d * 32 + jq * 8;
    *(s16x8*)dst = o;
}

// ---------------------------------------------------------------- precompute u.k_j and vb.p_r (bf16 in; k/p pre-scaled)
__global__ __launch_bounds__(256) void ukvb_kernel(const u16* __restrict__ k,
                                                   const u16* __restrict__ pp,
                                                   const float* __restrict__ u,
                                                   const float* __restrict__ vb,
                                                   float* __restrict__ ukg,
                                                   float* __restrict__ vbg) {
    int jid = blockIdx.x * 256 + threadIdx.x;
    const u16* src; const float* vec; float* dst; int idx;
    if (jid < 2 * Hh * Sx) {
        int j = jid & 2047, h = (jid >> 11) & 15, b = jid >> 15;
        src = k + ((size_t)(b * Sx + j)) * Dm + h * 64;
        vec = u + h * 64; dst = ukg; idx = jid;
    } else {
        int j2 = jid - 2 * Hh * Sx;
        int r = j2 & 2047, h = j2 >> 11;
        src = pp + (size_t)r * Dm + h * 64;
        vec = vb + h * 64; dst = vbg; idx = j2;
    }
    float s = 0.0f;
#pragma unroll
    for (int c = 0; c < 8; c++) {
        s16x8 kk = *(const s16x8*)(src + c * 8);
#pragma unroll
        for (int i = 0; i < 8; i++) s += bf2f((u16)kk[i]) * vec[c * 8 + i];
    }
    dst[idx] = s;
}

// ---------------------------------------------------------------- MFMA helpers for flash
__device__ __forceinline__ void wfill2(s16x8 a0, s16x8 a1, const u16* PW,
                                       int g, int l15, f32x4& d0, f32x4& d1) {
    f32x4 z = {0.f, 0.f, 0.f, 0.f};
    s16x8 b00 = *(const s16x8*)&PW[l15 * 72 + g * 8];
    s16x8 b01 = *(const s16x8*)&PW[l15 * 72 + 32 + g * 8];
    s16x8 b10 = *(const s16x8*)&PW[(16 + l15) * 72 + g * 8];
    s16x8 b11 = *(const s16x8*)&PW[(16 + l15) * 72 + 32 + g * 8];
    d0 = mfma16(a0, b00, z);
    d0 = mfma16(a1, b01, d0);
    d1 = mfma16(a0, b10, z);
    d1 = mfma16(a1, b11, d1);
}

// phase-specialized window fill: LDS slot addresses precomputed per phase (int4, static
// component access -> registers). Math identical to round-3 window_fill.
__device__ __forceinline__ void window_fill_p(s16x8 aq0, s16x8 aq1, s16x8 ab0, s16x8 ab1,
                                              const u16* PW, float* Ws,
                                              const float* __restrict__ vbb,
                                              int vstart, int4 wa0, int4 wa1,
                                              int g, int l15) {
    f32x4 e0, e1;
    if (vstart + 31 <= Sx) {
        wfill2(aq0, aq1, PW, g, l15, e0, e1);
    } else if (vstart > Sx) {
        wfill2(ab0, ab1, PW, g, l15, e0, e1);
    } else {
        f32x4 d0, d1, f0, f1;
        wfill2(aq0, aq1, PW, g, l15, d0, d1);
        wfill2(ab0, ab1, PW, g, l15, f0, f1);
        int v0m = vstart + l15, v1m = vstart + 16 + l15;
#pragma unroll
        for (int r = 0; r < 4; r++) {
            e0[r] = (v0m > Sx) ? f0[r] : d0[r];
            e1[r] = (v1m > Sx) ? f1[r] : d1[r];
        }
    }
    int v0 = vstart + l15, v1 = vstart + 16 + l15;
    int pc0 = v0 < Sx ? v0 : v0 - Sx - 1;
    int pc1 = v1 < Sx ? v1 : v1 - Sx - 1;
    float vb0 = (v0 == Sx) ? 0.0f : vbb[pc0];
    float vb1 = (v1 == Sx) ? 0.0f : vbb[pc1];
    bool z0 = (v0 == Sx), z1 = (v1 == Sx);
    Ws[wa0.x] = z0 ? 0.0f : e0[0] + vb0;
    Ws[wa0.y] = z0 ? 0.0f : e0[1] + vb0;
    Ws[wa0.z] = z0 ? 0.0f : e0[2] + vb0;
    Ws[wa0.w] = z0 ? 0.0f : e0[3] + vb0;
    Ws[wa1.x] = z1 ? 0.0f : e1[0] + vb1;
    Ws[wa1.y] = z1 ? 0.0f : e1[1] + vb1;
    Ws[wa1.z] = z1 ? 0.0f : e1[2] + vb1;
    Ws[wa1.w] = z1 ? 0.0f : e1[3] + vb1;
}

// one flash K-step. RA0/RA1: phase read addresses (int4). WA0/WA1: phase write addresses.
// DOFILL: compile-time 0/1. All t-dependence is via incremented registers (vst, puk, pK, pV).
#define FSTEP(RA0, RA1, WA0, WA1, DOFILL)                                        \
    {                                                                            \
        __syncthreads(); /* B0 */                                                \
        *(s16x8*)&Kt[rv * 72 + ch * 8] = rK;                                     \
        if (DOFILL) { *(s16x8*)&PW[rv * 72 + ch * 8] = rPW; }                    \
        s16x8 bv0 = *(const s16x8*)(pV);                                         \
        s16x8 bv1 = *(const s16x8*)(pV + 512);                                   \
        s16x8 bv2 = *(const s16x8*)(pV + 1024);                                  \
        s16x8 bv3 = *(const s16x8*)(pV + 1536);                                  \
        pV += 2048;                                                              \
        pK += 32 * Dm;                                                           \
        rK = *(const s16x8*)pK;                                                  \
        {                                                                        \
            int vv = vst + 32 + rv;                                              \
            s16x8 z8 = {0, 0, 0, 0, 0, 0, 0, 0};                                 \
            if (vv != Sx) {                                                      \
                int pc = vv < Sx ? vv : vv - Sx - 1;                             \
                if (pc > Sx - 1) pc = Sx - 1;                                    \
                z8 = *(const s16x8*)(ppb + (size_t)pc * Dm + ch * 8);            \
            }                                                                    \
            rPW = z8;                                                            \
        }                                                                        \
        float uk0 = puk[0];                                                      \
        float uk1 = puk[16];                                                     \
        puk += 32;                                                               \
        __syncthreads(); /* B1 */                                                \
        f32x4 s0, s1;                                                            \
        {                                                                        \
            f32x4 z = {0.f, 0.f, 0.f, 0.f};                                      \
            s16x8 bk00 = *(const s16x8*)&Kt[l15 * 72 + g * 8];                   \
            s16x8 bk01 = *(const s16x8*)&Kt[l15 * 72 + 32 + g * 8];              \
            s16x8 bk10 = *(const s16x8*)&Kt[(16 + l15) * 72 + g * 8];            \
            s16x8 bk11 = *(const s16x8*)&Kt[(16 + l15) * 72 + 32 + g * 8];       \
            s0 = mfma16(aq0, bk00, z);                                           \
            s0 = mfma16(aq1, bk01, s0);                                          \
            s1 = mfma16(aq0, bk10, z);                                           \
            s1 = mfma16(aq1, bk11, s1);                                          \
        }                                                                        \
        if (DOFILL) {                                                            \
            window_fill_p(aq0, aq1, ab0, ab1, PW, Ws, vbb, vst, WA0, WA1, g, l15); \
        }                                                                        \
        vst += 32;                                                               \
        float lg0[4], lg1[4];                                                    \
        lg0[0] = s0[0] + uk0 + Ws[RA0.x];                                        \
        lg0[1] = s0[1] + uk0 + Ws[RA0.y];                                        \
        lg0[2] = s0[2] + uk0 + Ws[RA0.z];                                        \
        lg0[3] = s0[3] + uk0 + Ws[RA0.w];                                        \
        lg1[0] = s1[0] + uk1 + Ws[RA1.x];                                        \
        lg1[1] = s1[1] + uk1 + Ws[RA1.y];                                        \
        lg1[2] = s1[2] + uk1 + Ws[RA1.z];                                        \
        lg1[3] = s1[3] + uk1 + Ws[RA1.w];                                        \
        float pmax = fmaxf(fmaxf(fmaxf(lg0[0], lg1[0]), fmaxf(lg0[1], lg1[1])),  \
                           fmaxf(fmaxf(lg0[2], lg1[2]), fmaxf(lg0[3], lg1[3]))); \
        if (__any(pmax > m_w + 8.0f)) {                                          \
            float mx = pmax;                                                     \
            _Pragma("unroll")                                                    \
            for (int o = 1; o < 64; o <<= 1) mx = fmaxf(mx, __shfl_xor(mx, o, 64)); \
            float alpha = EXP2(m_w - mx);                                        \
            m_w = mx;                                                            \
            l_i[0] *= alpha; l_i[1] *= alpha; l_i[2] *= alpha; l_i[3] *= alpha;  \
            _Pragma("unroll")                                                    \
            for (int nt = 0; nt < 4; nt++) {                                     \
                _Pragma("unroll")                                                \
                for (int r = 0; r < 4; r++) O[nt][r] *= alpha;                   \
            }                                                                    \
        }                                                                        \
        _Pragma("unroll")                                                        \
        for (int r = 0; r < 4; r++) {                                            \
            float e0v = EXP2(lg0[r] - m_w);                                      \
            float e1v = EXP2(lg1[r] - m_w);                                      \
            l_i[r] += e0v + e1v;                                                 \
            pa_store(PA, (rbase + r) * 40 + c0, (rbase + r) * 40 + c1, e0v, e1v); \
        }                                                                        \
        {                                                                        \
            s16x8 ap = *(const s16x8*)&PA[pard];                                 \
            O[0] = mfma16(ap, bv0, O[0]);                                        \
            O[1] = mfma16(ap, bv1, O[1]);                                        \
            O[2] = mfma16(ap, bv2, O[2]);                                        \
            O[3] = mfma16(ap, bv3, O[3]);                                        \
        }                                                                        \
    }

// ---------------------------------------------------------------- flash attention
// Round-3 structure + 3-phase address specialization: all mod-96 slot arithmetic
// (jm/sb/si/sl chains, ~50 VALU/iter) hoisted into 12 precomputed int4 address packs;
// main loop unrolled x3 so the phase is compile-time (no runtime-indexed arrays).
__global__ __launch_bounds__(256, 4) void flash_kernel(const u16* __restrict__ q,
                                                       const u16* __restrict__ k,
                                                       const u16* __restrict__ vt,
                                                       const u16* __restrict__ pp,
                                                       const float* __restrict__ ukg,
                                                       const float* __restrict__ vbg,
                                                       u16* __restrict__ head16) {
    __shared__ __align__(16) unsigned char smem[39424];
    float* Ws = (float*)smem;                    // 64*98*4 = 25088 (live whole kernel)
    u16*   Qs = (u16*)smem;                      // 65*72*2 = 9360  (prologue only, aliased)
    u16*   Kt = (u16*)(smem + 25088);            // 32*72*2 = 4608
    u16*   PW = (u16*)(smem + 29696);            // 32*72*2 = 4608
    u16*   PA = (u16*)(smem + 34304);            // 64*40*2 = 5120

    int tid = threadIdx.x, blk = blockIdx.x;
    int grp = (blk & 7) + 8 * (blk >> 8);        // 0..31 = b*16 + h
    int it  = (blk >> 3) & 31;
    int h = grp & 15, b = grp >> 4;
    int i0 = it * 64;
    int a0 = 1984 - i0;

    const u16* qb  = q  + ((size_t)b * Sx) * Dm + h * 64;
    const u16* kb  = k  + ((size_t)b * Sx) * Dm + h * 64;
    const u16* vtb = vt + ((size_t)(b * 16 + h) * 64) * 2048;
    const u16* ppb = pp + h * 64;
    const float* ukb = ukg + (size_t)(b * Hh + h) * Sx;
    const float* vbb = vbg + (size_t)h * Sx;

    int w = tid >> 6, ln = tid & 63, g = ln >> 4, l15 = ln & 15;
    int rv = tid >> 3, ch = tid & 7;
    int rbase = 16 * w + 4 * g;

    for (int c = tid; c < 65 * 8; c += 256) {
        int row = c >> 3, cc = c & 7;
        int i = i0 + row;
        s16x8 tv = {0, 0, 0, 0, 0, 0, 0, 0};
        if (i < Sx) tv = *(const s16x8*)(qb + (size_t)i * Dm + cc * 8);
        *(s16x8*)&Qs[row * 72 + cc * 8] = tv;
    }
    __syncthreads();

    s16x8 aq0 = *(const s16x8*)&Qs[(16 * w + l15) * 72 + g * 8];
    s16x8 aq1 = *(const s16x8*)&Qs[(16 * w + l15) * 72 + 32 + g * 8];
    s16x8 ab0 = *(const s16x8*)&Qs[(16 * w + 1 + l15) * 72 + g * 8];
    s16x8 ab1 = *(const s16x8*)&Qs[(16 * w + 1 + l15) * 72 + 32 + g * 8];
    __syncthreads();     // all waves done reading Qs before any Ws write (aliased)

    // phase-static LDS addresses: read jm in {63,95,31}, write slot base in {0,32,64}
    int4 ra0[3], ra1[3], wa0[3], wa1[3];
#pragma unroll
    for (int p = 0; p < 3; p++) {
        int jmp = (p == 0) ? 63 : (p == 1) ? 95 : 31;
        int si0 = jmp + l15; if (si0 >= 96) si0 -= 96;
        int si1 = si0 + 16;  if (si1 >= 96) si1 -= 96;
        int t0[4], t1[4], t2[4], t3[4];
#pragma unroll
        for (int r = 0; r < 4; r++) {
            int wr = (rbase + r) * 98;
            t0[r] = wr + si0;
            t1[r] = wr + si1;
            int b2 = 32 * p + rbase + r; if (b2 >= 96) b2 -= 96;
            int sl0 = b2 + l15; if (sl0 >= 96) sl0 -= 96;
            int sl1 = sl0 + 16; if (sl1 >= 96) sl1 -= 96;
            t2[r] = wr + sl0;
            t3[r] = wr + sl1;
        }
        ra0[p] = make_int4(t0[0], t0[1], t0[2], t0[3]);
        ra1[p] = make_int4(t1[0], t1[1], t1[2], t1[3]);
        wa0[p] = make_int4(t2[0], t2[1], t2[2], t2[3]);
        wa1[p] = make_int4(t3[0], t3[1], t3[2], t3[3]);
    }

    // prologue window fills: chunks at a0+0 / +32 / +64 use write phases 0/1/2
#pragma unroll
    for (int f = 0; f < 3; f++) {
        int vrb = f * 32;
        if (f) __syncthreads();
        {
            int vv = a0 + vrb + rv;
            s16x8 tv = {0, 0, 0, 0, 0, 0, 0, 0};
            if (vv != Sx) {
                int pc = vv < Sx ? vv : vv - Sx - 1;
                tv = *(const s16x8*)(ppb + (size_t)pc * Dm + ch * 8);
            }
            *(s16x8*)&PW[rv * 72 + ch * 8] = tv;
        }
        __syncthreads();
        window_fill_p(aq0, aq1, ab0, ab1, PW, Ws, vbb, a0 + vrb, wa0[f], wa1[f], g, l15);
    }

    f32x4 O[4] = {{0.f,0.f,0.f,0.f},{0.f,0.f,0.f,0.f},{0.f,0.f,0.f,0.f},{0.f,0.f,0.f,0.f}};
    float m_w = -1e30f;
    float l_i[4] = {0.f, 0.f, 0.f, 0.f};
    int cw = (g >= 2) ? 16 : 0;           // PA write column swizzle
    int crd = (l15 >> 3) << 4;            // PA read column swizzle
    int pard = (16 * w + l15) * 40 + ((g * 8 + crd) & 31);
    int c0 = l15 + cw;
    int c1 = l15 + 16 - cw;

    const u16* pK = kb + (size_t)rv * Dm + ch * 8;
    const u16* pV = vtb + l15 * 32 + g * 8;
    const float* puk = ukb + l15;
    s16x8 rK = *(const s16x8*)pK;
    s16x8 rPW = {0, 0, 0, 0, 0, 0, 0, 0};
    int vst = a0 + 64;                    // fill start for step t: a0 + 32t + 64

    // t = 0: read phase 0, no fill
    FSTEP(ra0[0], ra1[0], wa0[0], wa1[0], 0)
    // t = 1..63 = 21 x {read R1/W0, R2/W1, R0/W2}
#pragma unroll 1
    for (int tt = 0; tt < 21; tt++) {
        FSTEP(ra0[1], ra1[1], wa0[0], wa1[0], 1)
        FSTEP(ra0[2], ra1[2], wa0[1], wa1[1], 1)
        FSTEP(ra0[0], ra1[0], wa0[2], wa1[2], 1)
    }

#pragma unroll
    for (int r = 0; r < 4; r++) {
        float l = l_i[r];
#pragma unroll
        for (int o = 1; o < 16; o <<= 1) l += __shfl_xor(l, o, 64);
        float inv = 1.0f / l;
        int grow = i0 + rbase + r;
        u16* dst = head16 + (size_t)(b * Sx + grow) * 2048 + h * 64 + l15;
#pragma unroll
        for (int nt = 0; nt < 4; nt++) {
            float f = O[nt][r] * inv;
            u16 hh = f2bf(f);
            dst[16 * nt]        = hh;
            dst[1024 + 16 * nt] = f2bf(f - bf2f(hh));
        }
    }
}

// ---------------------------------------------------------------- launcher
extern "C" void kernel_launch(void* const* d_in, const int* in_sizes, int n_in,
                              void* d_out, int out_size, void* d_ws, size_t ws_size,
                              hipStream_t stream) {
    const float* x    = (const float*)d_in[0];
    const float* ln_g = (const float*)d_in[1];
    const float* ln_b = (const float*)d_in[2];
    const float* Wq   = (const float*)d_in[3];
    const float* bq   = (const float*)d_in[4];
    const float* Wk   = (const float*)d_in[5];
    const float* bk   = (const float*)d_in[6];
    const float* Wv   = (const float*)d_in[7];
    const float* bv   = (const float*)d_in[8];
    const float* Wp   = (const float*)d_in[9];
    const float* Wo   = (const float*)d_in[10];
    const float* bo   = (const float*)d_in[11];
    const float* ub   = (const float*)d_in[12];
    const float* vbias= (const float*)d_in[13];

    float* out = (float*)d_out;
    u16* base  = (u16*)d_ws;

    const int MROWS = 2 * Sx;                          // 4096
    u16* xn16   = base;                                // [4096][2048] hi|lo
    u16* head16 = base + 8u  * 1024 * 1024;            // [4096][2048] hi|lo
    u16* pe16   = base + 16u * 1024 * 1024;            // [2048][2048] hi|lo
    u16* qb16   = base + 20u * 1024 * 1024;            // [4096][1024]; k/v/p at +4M strides
    u16* kb16   = base + 24u * 1024 * 1024;
    u16* vb16   = base + 28u * 1024 * 1024;
    u16* pp16   = base + 32u * 1024 * 1024;            // [2048][1024]
    u16* vT16   = base + 34u * 1024 * 1024;            // [2][16][64][64][32]
    u16* WT     = base + 38u * 1024 * 1024;            // 5 x [1024][2048]
    float* ukg  = (float*)(base + 48u * 1024 * 1024);
    float* vbg  = ukg + 2 * Hh * Sx;

    ln_kernel<<<MROWS, 256, 0, stream>>>(x, ln_g, ln_b, xn16);
    pe_kernel<<<Sx * 512 / 256, 256, 0, stream>>>(pe16);

    dim3 gw(32, 32, 5);
    wconv_kernel<<<gw, 256, 0, stream>>>(Wq, Wk, Wv, Wp, Wo, WT);

    // fused Q/K/V/P projections: 768 QKV tiles + 128 pe tiles
    gemm128k<128><<<896, 256, 0, stream>>>(xn16, pe16, WT, bq, bk, bv, qb16, nullptr, 0);

    dim3 gv(Sx / 32, Hh, 2);
    vtrans_kernel<<<gv, 256, 0, stream>>>(vb16, vT16);

    ukvb_kernel<<<(2 * Hh * Sx + Hh * Sx) / 256, 256, 0, stream>>>(kb16, pp16, ub, vbias, ukg, vbg);

    flash_kernel<<<2 * Hh * 32, 256, 0, stream>>>(qb16, kb16, vT16, pp16, ukg, vbg, head16);

    gemm128k<64><<<dim3(8, 64), 256, 0, stream>>>(head16, nullptr, WT, bo, nullptr, nullptr, nullptr, out, 1);
}

// Round 7
// 372.494 us; speedup vs baseline: 1.5579x; 1.5579x over previous
//
#include <hip/hip_runtime.h>
#include <hip/hip_bf16.h>
#include <math.h>

#define Dm   1024
#define Hh   16
#define Sx   2048

typedef short s16x8 __attribute__((ext_vector_type(8)));
typedef float f32x4 __attribute__((ext_vector_type(4)));
typedef unsigned short u16;
typedef u16 u16x4 __attribute__((ext_vector_type(4)));

#if defined(__has_builtin)
#  if __has_builtin(__builtin_amdgcn_cvt_pk_bf16_f32)
#    define HAVE_PKBF16 1
typedef __bf16 bfv2 __attribute__((ext_vector_type(2)));
#  endif
#  if __has_builtin(__builtin_amdgcn_exp2f)
#    define EXP2(x) __builtin_amdgcn_exp2f(x)
#  endif
#endif
#ifndef EXP2
#  define EXP2(x) exp2f(x)
#endif

// logit scale folded into k and p: dh^-0.5 * log2(e)
#define ATT_SCALE 0.1803368801111204f

__device__ __forceinline__ float wave_sum64(float v) {
#pragma unroll
    for (int o = 32; o > 0; o >>= 1) v += __shfl_xor(v, o, 64);
    return v;
}
__device__ __forceinline__ u16 f2bf(float x) {
    unsigned int u = __float_as_uint(x);
    unsigned int r = u + 0x7FFFu + ((u >> 16) & 1u);
    return (u16)(r >> 16);
}
__device__ __forceinline__ float bf2f(u16 h) {
    return __uint_as_float(((unsigned int)h) << 16);
}
__device__ __forceinline__ f32x4 mfma16(s16x8 a, s16x8 b, f32x4 c) {
    return __builtin_amdgcn_mfma_f32_16x16x32_bf16(a, b, c, 0, 0, 0);
}
// direct global->LDS DMA, 16B/lane; LDS dest = wave-uniform base + lane*16
__device__ __forceinline__ void gl16(const u16* gp, u16* lp) {
    __builtin_amdgcn_global_load_lds(
        (__attribute__((address_space(1))) void*)(gp),
        (__attribute__((address_space(3))) void*)(lp), 16, 0, 0);
}

// ---------------------------------------------------------------- LayerNorm -> pre-split bf16 hi|lo
__global__ __launch_bounds__(256) void ln_kernel(const float* __restrict__ x,
                                                 const float* __restrict__ g,
                                                 const float* __restrict__ b,
                                                 u16* __restrict__ out16) {
    int row = blockIdx.x;
    int tid = threadIdx.x;
    const float4* xr = (const float4*)(x + (size_t)row * Dm);
    float4 v = xr[tid];
    float s  = v.x + v.y + v.z + v.w;
    float ss = v.x * v.x + v.y * v.y + v.z * v.z + v.w * v.w;
    __shared__ float rbuf[8];
    s  = wave_sum64(s);
    ss = wave_sum64(ss);
    if ((tid & 63) == 0) { rbuf[tid >> 6] = s; rbuf[4 + (tid >> 6)] = ss; }
    __syncthreads();
    float mean = (rbuf[0] + rbuf[1] + rbuf[2] + rbuf[3]) * (1.0f / Dm);
    float msq  = (rbuf[4] + rbuf[5] + rbuf[6] + rbuf[7]) * (1.0f / Dm);
    float var  = msq - mean * mean;
    float rstd = 1.0f / sqrtf(var + 1e-5f);
    float4 gg = ((const float4*)g)[tid];
    float4 bb = ((const float4*)b)[tid];
    float o[4];
    o[0] = (v.x - mean) * rstd * gg.x + bb.x;
    o[1] = (v.y - mean) * rstd * gg.y + bb.y;
    o[2] = (v.z - mean) * rstd * gg.z + bb.z;
    o[3] = (v.w - mean) * rstd * gg.w + bb.w;
    u16x4 hi, lo;
#pragma unroll
    for (int i = 0; i < 4; i++) {
        u16 h = f2bf(o[i]);
        hi[i] = h;
        lo[i] = f2bf(o[i] - bf2f(h));
    }
    *(u16x4*)&out16[(size_t)row * 2048 + tid * 4]        = hi;
    *(u16x4*)&out16[(size_t)row * 2048 + 1024 + tid * 4] = lo;
}

// ---------------------------------------------------------------- sinusoidal PE -> pre-split bf16
// fp32 transcendentals (validated round 6: absmax unchanged; double path is VALU-emulated)
__global__ __launch_bounds__(256) void pe_kernel(u16* __restrict__ pe16) {
    int idx = blockIdx.x * 256 + threadIdx.x;
    int r = idx >> 9;
    int t = idx & 511;
    float div = expf((float)(2 * t) * (-9.210340371976184f / 1024.0f));
    float ang = (float)r * div;
    float sv, cv;
    sincosf(ang, &sv, &cv);
    u16 sh = f2bf(sv), chh = f2bf(cv);
    u16* row = pe16 + (size_t)r * 2048;
    row[2 * t]            = sh;
    row[2 * t + 1]        = chh;
    row[1024 + 2 * t]     = f2bf(sv - bf2f(sh));
    row[1024 + 2 * t + 1] = f2bf(cv - bf2f(chh));
}

// ---------------------------------------------------------------- weight transpose + bf16 hi/lo split
__global__ __launch_bounds__(256) void wconv_kernel(const float* __restrict__ W0,
                                                    const float* __restrict__ W1,
                                                    const float* __restrict__ W2,
                                                    const float* __restrict__ W3,
                                                    const float* __restrict__ W4,
                                                    u16* __restrict__ WT) {
    int wz = blockIdx.z;
    const float* W = (wz == 0) ? W0 : (wz == 1) ? W1 : (wz == 2) ? W2 : (wz == 3) ? W3 : W4;
    u16* T = WT + (size_t)wz * 1024 * 2048;
    __shared__ float tile[32][33];
    int n0 = blockIdx.x * 32, k0 = blockIdx.y * 32;
    int tx = threadIdx.x & 31, ty = threadIdx.x >> 5;
#pragma unroll
    for (int r = 0; r < 32; r += 8)
        tile[ty + r][tx] = W[(size_t)(k0 + ty + r) * 1024 + n0 + tx];
    __syncthreads();
#pragma unroll
    for (int r = 0; r < 32; r += 8) {
        int n = ty + r;
        float x = tile[tx][n];
        u16 h = f2bf(x);
        float rem = x - bf2f(h);
        T[(size_t)(n0 + n) * 2048 + k0 + tx]        = h;
        T[(size_t)(n0 + n) * 2048 + 1024 + k0 + tx] = f2bf(rem);
    }
}

// ---------------------------------------------------------------- bf16x3 MFMA GEMM, global_load_lds staging
// BMT x 128 tile, direct global->LDS DMA with both-sides XOR swizzle (round-5 proven).
// NEW: widx==2 (V projection) writes the flash-ready transposed layout vT directly
// (same values, same f2bf -> bit-identical to the old vtrans output); vb16 is never
// materialized and the vtrans kernel is deleted.
template<int BMT>
__global__ __launch_bounds__(256, 4) void gemm128k(const u16* __restrict__ A,
                                                   const u16* __restrict__ A2,
                                                   const u16* __restrict__ WT,
                                                   const float* __restrict__ b0,
                                                   const float* __restrict__ b1,
                                                   const float* __restrict__ b2,
                                                   u16* __restrict__ Cb,
                                                   u16* __restrict__ VT,
                                                   float* __restrict__ C,
                                                   int mode) {
    constexpr int MT  = BMT / 32;
    constexpr int AC  = BMT / 32;
    constexpr int RPW = BMT / 4;
    __shared__ __align__(16) u16 AhL[BMT * 64];
    __shared__ __align__(16) u16 BhL[128 * 64];
    int tid = threadIdx.x;
    int gx, gy, widx;
    const u16* Asrc = A;
    if (mode == 0) {
        int bid = blockIdx.x;
        if (bid < 768) { gx = bid % 24; gy = bid / 24; widx = gx >> 3; gx &= 7; }
        else           { int r2 = bid - 768; gx = r2 & 7; gy = r2 >> 3; widx = 3; Asrc = A2; }
    } else {
        gx = blockIdx.x; gy = blockIdx.y; widx = 4;
    }
    int bn = gx * 128, bm = gy * BMT;
    const u16* Wb = WT + (size_t)widx * (1024 * 2048);
    const float* bias = (widx == 0) ? b0 : (widx == 1) ? b1 : (widx == 2) ? b2
                      : (widx == 4) ? b0 : nullptr;
    float csc = (widx == 1 || widx == 3) ? ATT_SCALE : 1.0f;

    int w = tid >> 6, ln = tid & 63, g = ln >> 4, l15 = ln & 15;
    int wm = (w & 1) * (BMT / 2), wn = (w >> 1) * 64;

    int key = ln >> 3;
    int cg  = (ln & 7) ^ key;
    int gcol = (cg < 4) ? cg * 8 : 1024 + (cg - 4) * 8;
    const u16* gA = Asrc + (size_t)(bm + w * RPW + key) * 2048 + gcol;
    const u16* gB = Wb   + (size_t)(bn + w * 32  + key) * 2048 + gcol;
    u16* lA = &AhL[(w * RPW) * 64];
    u16* lB = &BhL[(w * 32) * 64];

    int keyr = l15 & 7;
    int chH = (g ^ keyr) * 8;
    int chL = ((4 + g) ^ keyr) * 8;

    f32x4 acc[MT][4] = {};

    for (int k0 = 0; k0 < 1024; k0 += 32) {
#pragma unroll
        for (int c = 0; c < AC; c++)
            gl16(gA + c * (8 * 2048) + k0, lA + c * (8 * 64));
#pragma unroll
        for (int c = 0; c < 4; c++)
            gl16(gB + c * (8 * 2048) + k0, lB + c * (8 * 64));
        __syncthreads();

        s16x8 bhf[4], blf[4];
#pragma unroll
        for (int nt = 0; nt < 4; nt++) {
            int br = (wn + nt * 16 + l15) * 64;
            bhf[nt] = *(const s16x8*)&BhL[br + chH];
            blf[nt] = *(const s16x8*)&BhL[br + chL];
        }
#pragma unroll
        for (int mt = 0; mt < MT; mt++) {
            int ar = (wm + mt * 16 + l15) * 64;
            s16x8 ah = *(const s16x8*)&AhL[ar + chH];
            s16x8 al = *(const s16x8*)&AhL[ar + chL];
#pragma unroll
            for (int nt = 0; nt < 4; nt++) {
                acc[mt][nt] = mfma16(ah, bhf[nt], acc[mt][nt]);
                acc[mt][nt] = mfma16(al, bhf[nt], acc[mt][nt]);
                acc[mt][nt] = mfma16(ah, blf[nt], acc[mt][nt]);
            }
        }
        __syncthreads();
    }

    float bv4[4];
#pragma unroll
    for (int nt = 0; nt < 4; nt++)
        bv4[nt] = bias ? bias[bn + wn + nt * 16 + l15] : 0.0f;
    if (mode == 0) {
        if (widx == 2) {
            // transposed V write: vT[((b*16+h)*64 + jt)*2048 + d*32 + jr]
            // rows r=0..3 -> consecutive jr -> one aligned u16x4 store per (mt,nt)
            int bb  = bm >> 11;                     // blocks never straddle b (bm mult of 128)
            int hh  = (bn + wn) >> 6;               // wave-constant head
            int jt0 = ((bm & 2047) + wm) >> 5;
            int jr0 = g * 4;
#pragma unroll
            for (int mt = 0; mt < MT; mt++) {
#pragma unroll
                for (int nt = 0; nt < 4; nt++) {
                    u16x4 ov;
#pragma unroll
                    for (int r = 0; r < 4; r++)
                        ov[r] = f2bf(acc[mt][nt][r] + bv4[nt]);
                    int jt = jt0 + (mt >> 1);
                    int d  = 16 * nt + l15;
                    u16* dst = VT + ((size_t)(bb * 16 + hh) * 64 + jt) * 2048
                                  + d * 32 + (mt & 1) * 16 + jr0;
                    *(u16x4*)dst = ov;
                }
            }
        } else {
            u16* Co = Cb + (size_t)widx * (4096 * 1024);
#pragma unroll
            for (int mt = 0; mt < MT; mt++)
#pragma unroll
                for (int r = 0; r < 4; r++) {
                    int row = bm + wm + mt * 16 + g * 4 + r;
                    u16* cp = Co + (size_t)row * 1024 + bn + wn + l15;
#pragma unroll
                    for (int nt = 0; nt < 4; nt++)
                        cp[16 * nt] = f2bf((acc[mt][nt][r] + bv4[nt]) * csc);
                }
        }
    } else {
#pragma unroll
        for (int mt = 0; mt < MT; mt++)
#pragma unroll
            for (int r = 0; r < 4; r++) {
                int row = bm + wm + mt * 16 + g * 4 + r;
                float* cp = C + (size_t)row * 1024 + bn + wn + l15;
#pragma unroll
                for (int nt = 0; nt < 4; nt++)
                    cp[16 * nt] = acc[mt][nt][r] + bv4[nt];
            }
    }
}

// ---------------------------------------------------------------- precompute u.k_j and vb.p_r (bf16 in; k/p pre-scaled)
__global__ __launch_bounds__(256) void ukvb_kernel(const u16* __restrict__ k,
                                                   const u16* __restrict__ pp,
                                                   const float* __restrict__ u,
                                                   const float* __restrict__ vb,
                                                   float* __restrict__ ukg,
                                                   float* __restrict__ vbg) {
    int jid = blockIdx.x * 256 + threadIdx.x;
    const u16* src; const float* vec; float* dst; int idx;
    if (jid < 2 * Hh * Sx) {
        int j = jid & 2047, h = (jid >> 11) & 15, b = jid >> 15;
        src = k + ((size_t)(b * Sx + j)) * Dm + h * 64;
        vec = u + h * 64; dst = ukg; idx = jid;
    } else {
        int j2 = jid - 2 * Hh * Sx;
        int r = j2 & 2047, h = j2 >> 11;
        src = pp + (size_t)r * Dm + h * 64;
        vec = vb + h * 64; dst = vbg; idx = j2;
    }
    float s = 0.0f;
#pragma unroll
    for (int c = 0; c < 8; c++) {
        s16x8 kk = *(const s16x8*)(src + c * 8);
#pragma unroll
        for (int i = 0; i < 8; i++) s += bf2f((u16)kk[i]) * vec[c * 8 + i];
    }
    dst[idx] = s;
}

// ---------------------------------------------------------------- MFMA helpers for flash
__device__ __forceinline__ void wfill2(s16x8 a0, s16x8 a1, const u16* PW,
                                       int g, int l15, f32x4& d0, f32x4& d1) {
    f32x4 z = {0.f, 0.f, 0.f, 0.f};
    s16x8 b00 = *(const s16x8*)&PW[l15 * 72 + g * 8];
    s16x8 b01 = *(const s16x8*)&PW[l15 * 72 + 32 + g * 8];
    s16x8 b10 = *(const s16x8*)&PW[(16 + l15) * 72 + g * 8];
    s16x8 b11 = *(const s16x8*)&PW[(16 + l15) * 72 + 32 + g * 8];
    d0 = mfma16(a0, b00, z);
    d0 = mfma16(a1, b01, d0);
    d1 = mfma16(a0, b10, z);
    d1 = mfma16(a1, b11, d1);
}

// fill window chunk: skewed circular slots, physical = (logical_vr + row) % 96, stride 98
__device__ __forceinline__ void window_fill(s16x8 aq0, s16x8 aq1, s16x8 ab0, s16x8 ab1,
                                            const u16* PW, float* Ws,
                                            const float* __restrict__ vbb,
                                            int vstart, int sb, int rbase, int g, int l15) {
    f32x4 e0, e1;
    if (vstart + 31 <= Sx) {
        wfill2(aq0, aq1, PW, g, l15, e0, e1);
    } else if (vstart > Sx) {
        wfill2(ab0, ab1, PW, g, l15, e0, e1);
    } else {
        f32x4 d0, d1, f0, f1;
        wfill2(aq0, aq1, PW, g, l15, d0, d1);
        wfill2(ab0, ab1, PW, g, l15, f0, f1);
        int v0 = vstart + l15, v1 = vstart + 16 + l15;
#pragma unroll
        for (int r = 0; r < 4; r++) {
            e0[r] = (v0 > Sx) ? f0[r] : d0[r];
            e1[r] = (v1 > Sx) ? f1[r] : d1[r];
        }
    }
    int v0 = vstart + l15, v1 = vstart + 16 + l15;
    int pc0 = v0 < Sx ? v0 : v0 - Sx - 1;
    int pc1 = v1 < Sx ? v1 : v1 - Sx - 1;
    float vb0 = (v0 == Sx) ? 0.0f : vbb[pc0];
    float vb1 = (v1 == Sx) ? 0.0f : vbb[pc1];
    int bs = sb + rbase;
#pragma unroll
    for (int r = 0; r < 4; r++) {
        int b2 = bs + r; if (b2 >= 96) b2 -= 96;
        int sl0 = b2 + l15; if (sl0 >= 96) sl0 -= 96;
        int sl1 = sl0 + 16; if (sl1 >= 96) sl1 -= 96;
        Ws[(rbase + r) * 98 + sl0] = (v0 == Sx) ? 0.0f : e0[r] + vb0;
        Ws[(rbase + r) * 98 + sl1] = (v1 == Sx) ? 0.0f : e1[r] + vb1;
    }
}

// ---------------------------------------------------------------- flash attention (round-5 exact, frozen)
// Round-6 lesson: adding loop-carried address state spills to scratch at this kernel's
// 64-VGPR fit (FETCH 15.6 MB -> 415 MB). Keep inline mod-96 arithmetic.
__global__ __launch_bounds__(256, 4) void flash_kernel(const u16* __restrict__ q,
                                                       const u16* __restrict__ k,
                                                       const u16* __restrict__ vt,
                                                       const u16* __restrict__ pp,
                                                       const float* __restrict__ ukg,
                                                       const float* __restrict__ vbg,
                                                       u16* __restrict__ head16) {
    __shared__ __align__(16) unsigned char smem[39424];
    float* Ws = (float*)smem;                    // 64*98*4 = 25088 (live whole kernel)
    u16*   Qs = (u16*)smem;                      // 65*72*2 = 9360  (prologue only, aliased)
    u16*   Kt = (u16*)(smem + 25088);            // 32*72*2 = 4608
    u16*   PW = (u16*)(smem + 29696);            // 32*72*2 = 4608
    u16*   PA = (u16*)(smem + 34304);            // 64*40*2 = 5120

    int tid = threadIdx.x, blk = blockIdx.x;
    int grp = (blk & 7) + 8 * (blk >> 8);        // 0..31 = b*16 + h
    int it  = (blk >> 3) & 31;
    int h = grp & 15, b = grp >> 4;
    int i0 = it * 64;
    int a0 = 1984 - i0;

    const u16* qb  = q  + ((size_t)b * Sx) * Dm + h * 64;
    const u16* kb  = k  + ((size_t)b * Sx) * Dm + h * 64;
    const u16* vtb = vt + ((size_t)(b * 16 + h) * 64) * 2048;
    const u16* ppb = pp + h * 64;
    const float* ukb = ukg + (size_t)(b * Hh + h) * Sx;
    const float* vbb = vbg + (size_t)h * Sx;

    int w = tid >> 6, ln = tid & 63, g = ln >> 4, l15 = ln & 15;
    int rv = tid >> 3, ch = tid & 7;
    int rbase = 16 * w + 4 * g;

    for (int c = tid; c < 65 * 8; c += 256) {
        int row = c >> 3, cc = c & 7;
        int i = i0 + row;
        s16x8 tv = {0, 0, 0, 0, 0, 0, 0, 0};
        if (i < Sx) tv = *(const s16x8*)(qb + (size_t)i * Dm + cc * 8);
        *(s16x8*)&Qs[row * 72 + cc * 8] = tv;
    }
    __syncthreads();

    s16x8 aq0 = *(const s16x8*)&Qs[(16 * w + l15) * 72 + g * 8];
    s16x8 aq1 = *(const s16x8*)&Qs[(16 * w + l15) * 72 + 32 + g * 8];
    s16x8 ab0 = *(const s16x8*)&Qs[(16 * w + 1 + l15) * 72 + g * 8];
    s16x8 ab1 = *(const s16x8*)&Qs[(16 * w + 1 + l15) * 72 + 32 + g * 8];
    __syncthreads();     // all waves done reading Qs before any Ws write (aliased)

    for (int f = 0; f < 3; f++) {
        int vrb = f * 32;
        if (f) __syncthreads();
        {
            int vv = a0 + vrb + rv;
            s16x8 tv = {0, 0, 0, 0, 0, 0, 0, 0};
            if (vv != Sx) {
                int pc = vv < Sx ? vv : vv - Sx - 1;
                tv = *(const s16x8*)(ppb + (size_t)pc * Dm + ch * 8);
            }
            *(s16x8*)&PW[rv * 72 + ch * 8] = tv;
        }
        __syncthreads();
        window_fill(aq0, aq1, ab0, ab1, PW, Ws, vbb, a0 + vrb, vrb, rbase, g, l15);
    }

    f32x4 O[4] = {{0.f,0.f,0.f,0.f},{0.f,0.f,0.f,0.f},{0.f,0.f,0.f,0.f},{0.f,0.f,0.f,0.f}};
    float m_w = -1e30f;
    float l_i[4] = {0.f, 0.f, 0.f, 0.f};
    int wro[4];
#pragma unroll
    for (int r = 0; r < 4; r++) wro[r] = (rbase + r) * 98;
    int sb = 0;
    int jm = 63;
    int cw = (g >= 2) ? 16 : 0;
    int crd = (l15 >> 3) << 4;
    int pard = (16 * w + l15) * 40 + ((g * 8 + crd) & 31);

    const u16* pK = kb + (size_t)rv * Dm + ch * 8;
    const u16* pV = vtb + l15 * 32 + g * 8;
    s16x8 rK = *(const s16x8*)pK;
    s16x8 rPW = {0, 0, 0, 0, 0, 0, 0, 0};

    for (int t = 0; t < 64; t++) {
        int j0 = t * 32;
        __syncthreads();   // B0
        *(s16x8*)&Kt[rv * 72 + ch * 8] = rK;
        if (t >= 1) *(s16x8*)&PW[rv * 72 + ch * 8] = rPW;

        s16x8 bv0 = *(const s16x8*)(pV);
        s16x8 bv1 = *(const s16x8*)(pV + 512);
        s16x8 bv2 = *(const s16x8*)(pV + 1024);
        s16x8 bv3 = *(const s16x8*)(pV + 1536);
        pV += 2048;

        pK += 32 * Dm;
        rK = *(const s16x8*)pK;
        {
            int vv = a0 + (t + 3) * 32 + rv;
            s16x8 z8 = {0, 0, 0, 0, 0, 0, 0, 0};
            if (vv != Sx) {
                int pc = vv < Sx ? vv : vv - Sx - 1;
                if (pc > Sx - 1) pc = Sx - 1;
                z8 = *(const s16x8*)(ppb + (size_t)pc * Dm + ch * 8);
            }
            rPW = z8;
        }
        float uk0 = ukb[j0 + l15];
        float uk1 = ukb[j0 + 16 + l15];
        __syncthreads();   // B1

        f32x4 s0, s1;
        {
            f32x4 z = {0.f, 0.f, 0.f, 0.f};
            s16x8 bk00 = *(const s16x8*)&Kt[l15 * 72 + g * 8];
            s16x8 bk01 = *(const s16x8*)&Kt[l15 * 72 + 32 + g * 8];
            s16x8 bk10 = *(const s16x8*)&Kt[(16 + l15) * 72 + g * 8];
            s16x8 bk11 = *(const s16x8*)&Kt[(16 + l15) * 72 + 32 + g * 8];
            s0 = mfma16(aq0, bk00, z);
            s0 = mfma16(aq1, bk01, s0);
            s1 = mfma16(aq0, bk10, z);
            s1 = mfma16(aq1, bk11, s1);
        }

        if (t >= 1) {
            window_fill(aq0, aq1, ab0, ab1, PW, Ws, vbb, a0 + j0 + 64, sb, rbase, g, l15);
            sb += 32; if (sb >= 96) sb -= 96;
        }

        int si0 = jm + l15; if (si0 >= 96) si0 -= 96;
        int si1 = si0 + 16; if (si1 >= 96) si1 -= 96;
        jm += 32; if (jm >= 96) jm -= 96;
        float lg0[4], lg1[4];
#pragma unroll
        for (int r = 0; r < 4; r++) {
            lg0[r] = s0[r] + uk0 + Ws[wro[r] + si0];
            lg1[r] = s1[r] + uk1 + Ws[wro[r] + si1];
        }
        float pmax = fmaxf(fmaxf(fmaxf(lg0[0], lg1[0]), fmaxf(lg0[1], lg1[1])),
                           fmaxf(fmaxf(lg0[2], lg1[2]), fmaxf(lg0[3], lg1[3])));
        if (__any(pmax > m_w + 8.0f)) {
            float mx = pmax;
#pragma unroll
            for (int o = 1; o < 64; o <<= 1) mx = fmaxf(mx, __shfl_xor(mx, o, 64));
            float alpha = EXP2(m_w - mx);
            m_w = mx;
            l_i[0] *= alpha; l_i[1] *= alpha; l_i[2] *= alpha; l_i[3] *= alpha;
#pragma unroll
            for (int nt = 0; nt < 4; nt++)
#pragma unroll
                for (int r = 0; r < 4; r++) O[nt][r] *= alpha;
        }
        int c0 = l15 + cw;
        int c1 = l15 + 16 - cw;
#pragma unroll
        for (int r = 0; r < 4; r++) {
            float e0v = EXP2(lg0[r] - m_w);
            float e1v = EXP2(lg1[r] - m_w);
            l_i[r] += e0v + e1v;
#ifdef HAVE_PKBF16
            bfv2 pk2 = __builtin_amdgcn_cvt_pk_bf16_f32(e0v, e1v);
            PA[(rbase + r) * 40 + c0] = __builtin_bit_cast(u16, pk2[0]);
            PA[(rbase + r) * 40 + c1] = __builtin_bit_cast(u16, pk2[1]);
#else
            PA[(rbase + r) * 40 + c0] = f2bf(e0v);
            PA[(rbase + r) * 40 + c1] = f2bf(e1v);
#endif
        }

        {
            s16x8 ap = *(const s16x8*)&PA[pard];
            O[0] = mfma16(ap, bv0, O[0]);
            O[1] = mfma16(ap, bv1, O[1]);
            O[2] = mfma16(ap, bv2, O[2]);
            O[3] = mfma16(ap, bv3, O[3]);
        }
    }

#pragma unroll
    for (int r = 0; r < 4; r++) {
        float l = l_i[r];
#pragma unroll
        for (int o = 1; o < 16; o <<= 1) l += __shfl_xor(l, o, 64);
        float inv = 1.0f / l;
        int grow = i0 + rbase + r;
        u16* dst = head16 + (size_t)(b * Sx + grow) * 2048 + h * 64 + l15;
#pragma unroll
        for (int nt = 0; nt < 4; nt++) {
            float f = O[nt][r] * inv;
            u16 hh = f2bf(f);
            dst[16 * nt]        = hh;
            dst[1024 + 16 * nt] = f2bf(f - bf2f(hh));
        }
    }
}

// ---------------------------------------------------------------- launcher
extern "C" void kernel_launch(void* const* d_in, const int* in_sizes, int n_in,
                              void* d_out, int out_size, void* d_ws, size_t ws_size,
                              hipStream_t stream) {
    const float* x    = (const float*)d_in[0];
    const float* ln_g = (const float*)d_in[1];
    const float* ln_b = (const float*)d_in[2];
    const float* Wq   = (const float*)d_in[3];
    const float* bq   = (const float*)d_in[4];
    const float* Wk   = (const float*)d_in[5];
    const float* bk   = (const float*)d_in[6];
    const float* Wv   = (const float*)d_in[7];
    const float* bv   = (const float*)d_in[8];
    const float* Wp   = (const float*)d_in[9];
    const float* Wo   = (const float*)d_in[10];
    const float* bo   = (const float*)d_in[11];
    const float* ub   = (const float*)d_in[12];
    const float* vbias= (const float*)d_in[13];

    float* out = (float*)d_out;
    u16* base  = (u16*)d_ws;

    const int MROWS = 2 * Sx;                          // 4096
    u16* xn16   = base;                                // [4096][2048] hi|lo
    u16* head16 = base + 8u  * 1024 * 1024;            // [4096][2048] hi|lo
    u16* pe16   = base + 16u * 1024 * 1024;            // [2048][2048] hi|lo
    u16* qb16   = base + 20u * 1024 * 1024;            // [4096][1024]; k at +4M; p at +12M
    u16* kb16   = base + 24u * 1024 * 1024;
    u16* pp16   = base + 32u * 1024 * 1024;            // [2048][1024]
    u16* vT16   = base + 34u * 1024 * 1024;            // [2][16][64][64][32]
    u16* WT     = base + 38u * 1024 * 1024;            // 5 x [1024][2048]
    float* ukg  = (float*)(base + 48u * 1024 * 1024);
    float* vbg  = ukg + 2 * Hh * Sx;

    ln_kernel<<<MROWS, 256, 0, stream>>>(x, ln_g, ln_b, xn16);
    pe_kernel<<<Sx * 512 / 256, 256, 0, stream>>>(pe16);

    dim3 gw(32, 32, 5);
    wconv_kernel<<<gw, 256, 0, stream>>>(Wq, Wk, Wv, Wp, Wo, WT);

    // fused Q/K/V/P projections: 768 QKV tiles + 128 pe tiles; V writes vT16 directly
    gemm128k<128><<<896, 256, 0, stream>>>(xn16, pe16, WT, bq, bk, bv, qb16, vT16, nullptr, 0);

    ukvb_kernel<<<(2 * Hh * Sx + Hh * Sx) / 256, 256, 0, stream>>>(kb16, pp16, ub, vbias, ukg, vbg);

    flash_kernel<<<2 * Hh * 32, 256, 0, stream>>>(qb16, kb16, vT16, pp16, ukg, vbg, head16);

    gemm128k<64><<<dim3(8, 64), 256, 0, stream>>>(head16, nullptr, WT, bo, nullptr, nullptr, nullptr, nullptr, out, 1);
}

// Round 8
// 368.049 us; speedup vs baseline: 1.5767x; 1.0121x over previous
//
#include <hip/hip_runtime.h>
#include <hip/hip_bf16.h>
#include <math.h>

#define Dm   1024
#define Hh   16
#define Sx   2048

typedef short s16x8 __attribute__((ext_vector_type(8)));
typedef float f32x4 __attribute__((ext_vector_type(4)));
typedef unsigned short u16;
typedef u16 u16x4 __attribute__((ext_vector_type(4)));

#if defined(__has_builtin)
#  if __has_builtin(__builtin_amdgcn_cvt_pk_bf16_f32)
#    define HAVE_PKBF16 1
typedef __bf16 bfv2 __attribute__((ext_vector_type(2)));
#  endif
#  if __has_builtin(__builtin_amdgcn_exp2f)
#    define EXP2(x) __builtin_amdgcn_exp2f(x)
#  endif
#endif
#ifndef EXP2
#  define EXP2(x) exp2f(x)
#endif

// logit scale folded into k and p: dh^-0.5 * log2(e)
#define ATT_SCALE 0.1803368801111204f

// barrier with LDS-visibility only (no vmcnt drain): in-flight global prefetches
// stay outstanding across the barrier; their results are register deps the compiler
// waits on at the use site. This is the AITER/HK "never vmcnt(0) in the loop" pattern.
#define BARRIER_LGKM() asm volatile("s_waitcnt lgkmcnt(0)\n\ts_barrier" ::: "memory")

__device__ __forceinline__ float wave_sum64(float v) {
#pragma unroll
    for (int o = 32; o > 0; o >>= 1) v += __shfl_xor(v, o, 64);
    return v;
}
__device__ __forceinline__ u16 f2bf(float x) {
    unsigned int u = __float_as_uint(x);
    unsigned int r = u + 0x7FFFu + ((u >> 16) & 1u);
    return (u16)(r >> 16);
}
__device__ __forceinline__ float bf2f(u16 h) {
    return __uint_as_float(((unsigned int)h) << 16);
}
__device__ __forceinline__ f32x4 mfma16(s16x8 a, s16x8 b, f32x4 c) {
    return __builtin_amdgcn_mfma_f32_16x16x32_bf16(a, b, c, 0, 0, 0);
}
// direct global->LDS DMA, 16B/lane; LDS dest = wave-uniform base + lane*16
__device__ __forceinline__ void gl16(const u16* gp, u16* lp) {
    __builtin_amdgcn_global_load_lds(
        (__attribute__((address_space(1))) void*)(gp),
        (__attribute__((address_space(3))) void*)(lp), 16, 0, 0);
}

// ---------------------------------------------------------------- LayerNorm -> pre-split bf16 hi|lo
__global__ __launch_bounds__(256) void ln_kernel(const float* __restrict__ x,
                                                 const float* __restrict__ g,
                                                 const float* __restrict__ b,
                                                 u16* __restrict__ out16) {
    int row = blockIdx.x;
    int tid = threadIdx.x;
    const float4* xr = (const float4*)(x + (size_t)row * Dm);
    float4 v = xr[tid];
    float s  = v.x + v.y + v.z + v.w;
    float ss = v.x * v.x + v.y * v.y + v.z * v.z + v.w * v.w;
    __shared__ float rbuf[8];
    s  = wave_sum64(s);
    ss = wave_sum64(ss);
    if ((tid & 63) == 0) { rbuf[tid >> 6] = s; rbuf[4 + (tid >> 6)] = ss; }
    __syncthreads();
    float mean = (rbuf[0] + rbuf[1] + rbuf[2] + rbuf[3]) * (1.0f / Dm);
    float msq  = (rbuf[4] + rbuf[5] + rbuf[6] + rbuf[7]) * (1.0f / Dm);
    float var  = msq - mean * mean;
    float rstd = 1.0f / sqrtf(var + 1e-5f);
    float4 gg = ((const float4*)g)[tid];
    float4 bb = ((const float4*)b)[tid];
    float o[4];
    o[0] = (v.x - mean) * rstd * gg.x + bb.x;
    o[1] = (v.y - mean) * rstd * gg.y + bb.y;
    o[2] = (v.z - mean) * rstd * gg.z + bb.z;
    o[3] = (v.w - mean) * rstd * gg.w + bb.w;
    u16x4 hi, lo;
#pragma unroll
    for (int i = 0; i < 4; i++) {
        u16 h = f2bf(o[i]);
        hi[i] = h;
        lo[i] = f2bf(o[i] - bf2f(h));
    }
    *(u16x4*)&out16[(size_t)row * 2048 + tid * 4]        = hi;
    *(u16x4*)&out16[(size_t)row * 2048 + 1024 + tid * 4] = lo;
}

// ---------------------------------------------------------------- sinusoidal PE -> pre-split bf16
__global__ __launch_bounds__(256) void pe_kernel(u16* __restrict__ pe16) {
    int idx = blockIdx.x * 256 + threadIdx.x;
    int r = idx >> 9;
    int t = idx & 511;
    float div = expf((float)(2 * t) * (-9.210340371976184f / 1024.0f));
    float ang = (float)r * div;
    float sv, cv;
    sincosf(ang, &sv, &cv);
    u16 sh = f2bf(sv), chh = f2bf(cv);
    u16* row = pe16 + (size_t)r * 2048;
    row[2 * t]            = sh;
    row[2 * t + 1]        = chh;
    row[1024 + 2 * t]     = f2bf(sv - bf2f(sh));
    row[1024 + 2 * t + 1] = f2bf(cv - bf2f(chh));
}

// ---------------------------------------------------------------- weight transpose + bf16 hi/lo split
__global__ __launch_bounds__(256) void wconv_kernel(const float* __restrict__ W0,
                                                    const float* __restrict__ W1,
                                                    const float* __restrict__ W2,
                                                    const float* __restrict__ W3,
                                                    const float* __restrict__ W4,
                                                    u16* __restrict__ WT) {
    int wz = blockIdx.z;
    const float* W = (wz == 0) ? W0 : (wz == 1) ? W1 : (wz == 2) ? W2 : (wz == 3) ? W3 : W4;
    u16* T = WT + (size_t)wz * 1024 * 2048;
    __shared__ float tile[32][33];
    int n0 = blockIdx.x * 32, k0 = blockIdx.y * 32;
    int tx = threadIdx.x & 31, ty = threadIdx.x >> 5;
#pragma unroll
    for (int r = 0; r < 32; r += 8)
        tile[ty + r][tx] = W[(size_t)(k0 + ty + r) * 1024 + n0 + tx];
    __syncthreads();
#pragma unroll
    for (int r = 0; r < 32; r += 8) {
        int n = ty + r;
        float x = tile[tx][n];
        u16 h = f2bf(x);
        float rem = x - bf2f(h);
        T[(size_t)(n0 + n) * 2048 + k0 + tx]        = h;
        T[(size_t)(n0 + n) * 2048 + 1024 + k0 + tx] = f2bf(rem);
    }
}

// ---------------------------------------------------------------- bf16x3 MFMA GEMM, global_load_lds staging
// BMT x 128 tile, direct global->LDS DMA with both-sides XOR swizzle (round-5 proven).
// widx==2 writes the flash-ready transposed V layout directly (round-7 proven).
// NEW: widx==1/3 fuse the u.k / vb.p reductions into the epilogue (each wave's 64 cols
// = one head; in-lane 4-term sum over nt + 16-lane shfl reduce, computed from the SAME
// rounded bf16 values being stored) -> the separate ukvb kernel is deleted.
template<int BMT>
__global__ __launch_bounds__(256, 4) void gemm128k(const u16* __restrict__ A,
                                                   const u16* __restrict__ A2,
                                                   const u16* __restrict__ WT,
                                                   const float* __restrict__ b0,
                                                   const float* __restrict__ b1,
                                                   const float* __restrict__ b2,
                                                   const float* __restrict__ ubv,
                                                   const float* __restrict__ vbv,
                                                   float* __restrict__ ukg,
                                                   float* __restrict__ vbg,
                                                   u16* __restrict__ Cb,
                                                   u16* __restrict__ VT,
                                                   float* __restrict__ C,
                                                   int mode) {
    constexpr int MT  = BMT / 32;
    constexpr int AC  = BMT / 32;
    constexpr int RPW = BMT / 4;
    __shared__ __align__(16) u16 AhL[BMT * 64];
    __shared__ __align__(16) u16 BhL[128 * 64];
    int tid = threadIdx.x;
    int gx, gy, widx;
    const u16* Asrc = A;
    if (mode == 0) {
        int bid = blockIdx.x;
        if (bid < 768) { gx = bid % 24; gy = bid / 24; widx = gx >> 3; gx &= 7; }
        else           { int r2 = bid - 768; gx = r2 & 7; gy = r2 >> 3; widx = 3; Asrc = A2; }
    } else {
        gx = blockIdx.x; gy = blockIdx.y; widx = 4;
    }
    int bn = gx * 128, bm = gy * BMT;
    const u16* Wb = WT + (size_t)widx * (1024 * 2048);
    const float* bias = (widx == 0) ? b0 : (widx == 1) ? b1 : (widx == 2) ? b2
                      : (widx == 4) ? b0 : nullptr;
    float csc = (widx == 1 || widx == 3) ? ATT_SCALE : 1.0f;

    int w = tid >> 6, ln = tid & 63, g = ln >> 4, l15 = ln & 15;
    int wm = (w & 1) * (BMT / 2), wn = (w >> 1) * 64;

    int key = ln >> 3;
    int cg  = (ln & 7) ^ key;
    int gcol = (cg < 4) ? cg * 8 : 1024 + (cg - 4) * 8;
    const u16* gA = Asrc + (size_t)(bm + w * RPW + key) * 2048 + gcol;
    const u16* gB = Wb   + (size_t)(bn + w * 32  + key) * 2048 + gcol;
    u16* lA = &AhL[(w * RPW) * 64];
    u16* lB = &BhL[(w * 32) * 64];

    int keyr = l15 & 7;
    int chH = (g ^ keyr) * 8;
    int chL = ((4 + g) ^ keyr) * 8;

    f32x4 acc[MT][4] = {};

    for (int k0 = 0; k0 < 1024; k0 += 32) {
#pragma unroll
        for (int c = 0; c < AC; c++)
            gl16(gA + c * (8 * 2048) + k0, lA + c * (8 * 64));
#pragma unroll
        for (int c = 0; c < 4; c++)
            gl16(gB + c * (8 * 2048) + k0, lB + c * (8 * 64));
        __syncthreads();

        s16x8 bhf[4], blf[4];
#pragma unroll
        for (int nt = 0; nt < 4; nt++) {
            int br = (wn + nt * 16 + l15) * 64;
            bhf[nt] = *(const s16x8*)&BhL[br + chH];
            blf[nt] = *(const s16x8*)&BhL[br + chL];
        }
#pragma unroll
        for (int mt = 0; mt < MT; mt++) {
            int ar = (wm + mt * 16 + l15) * 64;
            s16x8 ah = *(const s16x8*)&AhL[ar + chH];
            s16x8 al = *(const s16x8*)&AhL[ar + chL];
#pragma unroll
            for (int nt = 0; nt < 4; nt++) {
                acc[mt][nt] = mfma16(ah, bhf[nt], acc[mt][nt]);
                acc[mt][nt] = mfma16(al, bhf[nt], acc[mt][nt]);
                acc[mt][nt] = mfma16(ah, blf[nt], acc[mt][nt]);
            }
        }
        __syncthreads();
    }

    float bv4[4];
#pragma unroll
    for (int nt = 0; nt < 4; nt++)
        bv4[nt] = bias ? bias[bn + wn + nt * 16 + l15] : 0.0f;
    if (mode == 0) {
        if (widx == 2) {
            // transposed V write: vT[((b*16+h)*64 + jt)*2048 + d*32 + jr]
            int bb  = bm >> 11;
            int hh  = (bn + wn) >> 6;
            int jt0 = ((bm & 2047) + wm) >> 5;
            int jr0 = g * 4;
#pragma unroll
            for (int mt = 0; mt < MT; mt++) {
#pragma unroll
                for (int nt = 0; nt < 4; nt++) {
                    u16x4 ov;
#pragma unroll
                    for (int r = 0; r < 4; r++)
                        ov[r] = f2bf(acc[mt][nt][r] + bv4[nt]);
                    int jt = jt0 + (mt >> 1);
                    int d  = 16 * nt + l15;
                    u16* dst = VT + ((size_t)(bb * 16 + hh) * 64 + jt) * 2048
                                  + d * 32 + (mt & 1) * 16 + jr0;
                    *(u16x4*)dst = ov;
                }
            }
        } else {
            u16* Co = Cb + (size_t)widx * (4096 * 1024);
            bool dored = (widx == 1 || widx == 3);
            int hh = (bn + wn) >> 6;
            float u4[4] = {0.f, 0.f, 0.f, 0.f};
            if (dored) {
                const float* uv = (widx == 1) ? ubv : vbv;
#pragma unroll
                for (int nt = 0; nt < 4; nt++) u4[nt] = uv[hh * 64 + 16 * nt + l15];
            }
#pragma unroll
            for (int mt = 0; mt < MT; mt++)
#pragma unroll
                for (int r = 0; r < 4; r++) {
                    int row = bm + wm + mt * 16 + g * 4 + r;
                    u16* cp = Co + (size_t)row * 1024 + bn + wn + l15;
                    u16 hv[4];
#pragma unroll
                    for (int nt = 0; nt < 4; nt++) {
                        hv[nt] = f2bf((acc[mt][nt][r] + bv4[nt]) * csc);
                        cp[16 * nt] = hv[nt];
                    }
                    if (dored) {
                        float s = bf2f(hv[0]) * u4[0] + bf2f(hv[1]) * u4[1]
                                + bf2f(hv[2]) * u4[2] + bf2f(hv[3]) * u4[3];
#pragma unroll
                        for (int o = 1; o < 16; o <<= 1) s += __shfl_xor(s, o, 64);
                        if (l15 == 0) {
                            if (widx == 1)
                                ukg[((size_t)((bm >> 11) * 16 + hh)) * 2048
                                    + ((bm & 2047) + wm + mt * 16 + g * 4 + r)] = s;
                            else
                                vbg[(size_t)hh * 2048 + (bm + wm + mt * 16 + g * 4 + r)] = s;
                        }
                    }
                }
        }
    } else {
#pragma unroll
        for (int mt = 0; mt < MT; mt++)
#pragma unroll
            for (int r = 0; r < 4; r++) {
                int row = bm + wm + mt * 16 + g * 4 + r;
                float* cp = C + (size_t)row * 1024 + bn + wn + l15;
#pragma unroll
                for (int nt = 0; nt < 4; nt++)
                    cp[16 * nt] = acc[mt][nt][r] + bv4[nt];
            }
    }
}

// ---------------------------------------------------------------- MFMA helpers for flash
__device__ __forceinline__ void wfill2(s16x8 a0, s16x8 a1, const u16* PW,
                                       int g, int l15, f32x4& d0, f32x4& d1) {
    f32x4 z = {0.f, 0.f, 0.f, 0.f};
    s16x8 b00 = *(const s16x8*)&PW[l15 * 72 + g * 8];
    s16x8 b01 = *(const s16x8*)&PW[l15 * 72 + 32 + g * 8];
    s16x8 b10 = *(const s16x8*)&PW[(16 + l15) * 72 + g * 8];
    s16x8 b11 = *(const s16x8*)&PW[(16 + l15) * 72 + 32 + g * 8];
    d0 = mfma16(a0, b00, z);
    d0 = mfma16(a1, b01, d0);
    d1 = mfma16(a0, b10, z);
    d1 = mfma16(a1, b11, d1);
}

// fill window chunk: skewed circular slots, physical = (logical_vr + row) % 96, stride 98
__device__ __forceinline__ void window_fill(s16x8 aq0, s16x8 aq1, s16x8 ab0, s16x8 ab1,
                                            const u16* PW, float* Ws,
                                            const float* __restrict__ vbb,
                                            int vstart, int sb, int rbase, int g, int l15) {
    f32x4 e0, e1;
    if (vstart + 31 <= Sx) {
        wfill2(aq0, aq1, PW, g, l15, e0, e1);
    } else if (vstart > Sx) {
        wfill2(ab0, ab1, PW, g, l15, e0, e1);
    } else {
        f32x4 d0, d1, f0, f1;
        wfill2(aq0, aq1, PW, g, l15, d0, d1);
        wfill2(ab0, ab1, PW, g, l15, f0, f1);
        int v0 = vstart + l15, v1 = vstart + 16 + l15;
#pragma unroll
        for (int r = 0; r < 4; r++) {
            e0[r] = (v0 > Sx) ? f0[r] : d0[r];
            e1[r] = (v1 > Sx) ? f1[r] : d1[r];
        }
    }
    int v0 = vstart + l15, v1 = vstart + 16 + l15;
    int pc0 = v0 < Sx ? v0 : v0 - Sx - 1;
    int pc1 = v1 < Sx ? v1 : v1 - Sx - 1;
    float vb0 = (v0 == Sx) ? 0.0f : vbb[pc0];
    float vb1 = (v1 == Sx) ? 0.0f : vbb[pc1];
    int bs = sb + rbase;
#pragma unroll
    for (int r = 0; r < 4; r++) {
        int b2 = bs + r; if (b2 >= 96) b2 -= 96;
        int sl0 = b2 + l15; if (sl0 >= 96) sl0 -= 96;
        int sl1 = sl0 + 16; if (sl1 >= 96) sl1 -= 96;
        Ws[(rbase + r) * 98 + sl0] = (v0 == Sx) ? 0.0f : e0[r] + vb0;
        Ws[(rbase + r) * 98 + sl1] = (v1 == Sx) ? 0.0f : e1[r] + vb1;
    }
}

// ---------------------------------------------------------------- flash attention (round-5 structure)
// NEW: in-loop barriers wait lgkmcnt only (no vmcnt drain) -- the per-iteration global
// prefetches (V/K/PW/uk) stay in flight across B1 instead of being drained ~20
// instructions after issue. Their results are register deps guarded at use sites.
__global__ __launch_bounds__(256, 4) void flash_kernel(const u16* __restrict__ q,
                                                       const u16* __restrict__ k,
                                                       const u16* __restrict__ vt,
                                                       const u16* __restrict__ pp,
                                                       const float* __restrict__ ukg,
                                                       const float* __restrict__ vbg,
                                                       u16* __restrict__ head16) {
    __shared__ __align__(16) unsigned char smem[39424];
    float* Ws = (float*)smem;                    // 64*98*4 = 25088 (live whole kernel)
    u16*   Qs = (u16*)smem;                      // 65*72*2 = 9360  (prologue only, aliased)
    u16*   Kt = (u16*)(smem + 25088);            // 32*72*2 = 4608
    u16*   PW = (u16*)(smem + 29696);            // 32*72*2 = 4608
    u16*   PA = (u16*)(smem + 34304);            // 64*40*2 = 5120

    int tid = threadIdx.x, blk = blockIdx.x;
    int grp = (blk & 7) + 8 * (blk >> 8);        // 0..31 = b*16 + h
    int it  = (blk >> 3) & 31;
    int h = grp & 15, b = grp >> 4;
    int i0 = it * 64;
    int a0 = 1984 - i0;

    const u16* qb  = q  + ((size_t)b * Sx) * Dm + h * 64;
    const u16* kb  = k  + ((size_t)b * Sx) * Dm + h * 64;
    const u16* vtb = vt + ((size_t)(b * 16 + h) * 64) * 2048;
    const u16* ppb = pp + h * 64;
    const float* ukb = ukg + (size_t)(b * Hh + h) * Sx;
    const float* vbb = vbg + (size_t)h * Sx;

    int w = tid >> 6, ln = tid & 63, g = ln >> 4, l15 = ln & 15;
    int rv = tid >> 3, ch = tid & 7;
    int rbase = 16 * w + 4 * g;

    for (int c = tid; c < 65 * 8; c += 256) {
        int row = c >> 3, cc = c & 7;
        int i = i0 + row;
        s16x8 tv = {0, 0, 0, 0, 0, 0, 0, 0};
        if (i < Sx) tv = *(const s16x8*)(qb + (size_t)i * Dm + cc * 8);
        *(s16x8*)&Qs[row * 72 + cc * 8] = tv;
    }
    __syncthreads();

    s16x8 aq0 = *(const s16x8*)&Qs[(16 * w + l15) * 72 + g * 8];
    s16x8 aq1 = *(const s16x8*)&Qs[(16 * w + l15) * 72 + 32 + g * 8];
    s16x8 ab0 = *(const s16x8*)&Qs[(16 * w + 1 + l15) * 72 + g * 8];
    s16x8 ab1 = *(const s16x8*)&Qs[(16 * w + 1 + l15) * 72 + 32 + g * 8];
    __syncthreads();     // all waves done reading Qs before any Ws write (aliased)

    for (int f = 0; f < 3; f++) {
        int vrb = f * 32;
        if (f) __syncthreads();
        {
            int vv = a0 + vrb + rv;
            s16x8 tv = {0, 0, 0, 0, 0, 0, 0, 0};
            if (vv != Sx) {
                int pc = vv < Sx ? vv : vv - Sx - 1;
                tv = *(const s16x8*)(ppb + (size_t)pc * Dm + ch * 8);
            }
            *(s16x8*)&PW[rv * 72 + ch * 8] = tv;
        }
        __syncthreads();
        window_fill(aq0, aq1, ab0, ab1, PW, Ws, vbb, a0 + vrb, vrb, rbase, g, l15);
    }

    f32x4 O[4] = {{0.f,0.f,0.f,0.f},{0.f,0.f,0.f,0.f},{0.f,0.f,0.f,0.f},{0.f,0.f,0.f,0.f}};
    float m_w = -1e30f;
    float l_i[4] = {0.f, 0.f, 0.f, 0.f};
    int wro[4];
#pragma unroll
    for (int r = 0; r < 4; r++) wro[r] = (rbase + r) * 98;
    int sb = 0;
    int jm = 63;
    int cw = (g >= 2) ? 16 : 0;
    int crd = (l15 >> 3) << 4;
    int pard = (16 * w + l15) * 40 + ((g * 8 + crd) & 31);

    const u16* pK = kb + (size_t)rv * Dm + ch * 8;
    const u16* pV = vtb + l15 * 32 + g * 8;
    s16x8 rK = *(const s16x8*)pK;
    s16x8 rPW = {0, 0, 0, 0, 0, 0, 0, 0};

    for (int t = 0; t < 64; t++) {
        int j0 = t * 32;
        BARRIER_LGKM();    // B0: Kt/PW reads of prev iter done (lgkm only)
        *(s16x8*)&Kt[rv * 72 + ch * 8] = rK;
        if (t >= 1) *(s16x8*)&PW[rv * 72 + ch * 8] = rPW;

        s16x8 bv0 = *(const s16x8*)(pV);
        s16x8 bv1 = *(const s16x8*)(pV + 512);
        s16x8 bv2 = *(const s16x8*)(pV + 1024);
        s16x8 bv3 = *(const s16x8*)(pV + 1536);
        pV += 2048;

        pK += 32 * Dm;
        rK = *(const s16x8*)pK;
        {
            int vv = a0 + (t + 3) * 32 + rv;
            s16x8 z8 = {0, 0, 0, 0, 0, 0, 0, 0};
            if (vv != Sx) {
                int pc = vv < Sx ? vv : vv - Sx - 1;
                if (pc > Sx - 1) pc = Sx - 1;
                z8 = *(const s16x8*)(ppb + (size_t)pc * Dm + ch * 8);
            }
            rPW = z8;
        }
        float uk0 = ukb[j0 + l15];
        float uk1 = ukb[j0 + 16 + l15];
        BARRIER_LGKM();    // B1: Kt/PW writes visible (lgkm only; prefetches stay in flight)

        f32x4 s0, s1;
        {
            f32x4 z = {0.f, 0.f, 0.f, 0.f};
            s16x8 bk00 = *(const s16x8*)&Kt[l15 * 72 + g * 8];
            s16x8 bk01 = *(const s16x8*)&Kt[l15 * 72 + 32 + g * 8];
            s16x8 bk10 = *(const s16x8*)&Kt[(16 + l15) * 72 + g * 8];
            s16x8 bk11 = *(const s16x8*)&Kt[(16 + l15) * 72 + 32 + g * 8];
            s0 = mfma16(aq0, bk00, z);
            s0 = mfma16(aq1, bk01, s0);
            s1 = mfma16(aq0, bk10, z);
            s1 = mfma16(aq1, bk11, s1);
        }

        if (t >= 1) {
            window_fill(aq0, aq1, ab0, ab1, PW, Ws, vbb, a0 + j0 + 64, sb, rbase, g, l15);
            sb += 32; if (sb >= 96) sb -= 96;
        }

        int si0 = jm + l15; if (si0 >= 96) si0 -= 96;
        int si1 = si0 + 16; if (si1 >= 96) si1 -= 96;
        jm += 32; if (jm >= 96) jm -= 96;
        float lg0[4], lg1[4];
#pragma unroll
        for (int r = 0; r < 4; r++) {
            lg0[r] = s0[r] + uk0 + Ws[wro[r] + si0];
            lg1[r] = s1[r] + uk1 + Ws[wro[r] + si1];
        }
        float pmax = fmaxf(fmaxf(fmaxf(lg0[0], lg1[0]), fmaxf(lg0[1], lg1[1])),
                           fmaxf(fmaxf(lg0[2], lg1[2]), fmaxf(lg0[3], lg1[3])));
        if (__any(pmax > m_w + 8.0f)) {
            float mx = pmax;
#pragma unroll
            for (int o = 1; o < 64; o <<= 1) mx = fmaxf(mx, __shfl_xor(mx, o, 64));
            float alpha = EXP2(m_w - mx);
            m_w = mx;
            l_i[0] *= alpha; l_i[1] *= alpha; l_i[2] *= alpha; l_i[3] *= alpha;
#pragma unroll
            for (int nt = 0; nt < 4; nt++)
#pragma unroll
                for (int r = 0; r < 4; r++) O[nt][r] *= alpha;
        }
        int c0 = l15 + cw;
        int c1 = l15 + 16 - cw;
#pragma unroll
        for (int r = 0; r < 4; r++) {
            float e0v = EXP2(lg0[r] - m_w);
            float e1v = EXP2(lg1[r] - m_w);
            l_i[r] += e0v + e1v;
#ifdef HAVE_PKBF16
            bfv2 pk2 = __builtin_amdgcn_cvt_pk_bf16_f32(e0v, e1v);
            PA[(rbase + r) * 40 + c0] = __builtin_bit_cast(u16, pk2[0]);
            PA[(rbase + r) * 40 + c1] = __builtin_bit_cast(u16, pk2[1]);
#else
            PA[(rbase + r) * 40 + c0] = f2bf(e0v);
            PA[(rbase + r) * 40 + c1] = f2bf(e1v);
#endif
        }

        {
            s16x8 ap = *(const s16x8*)&PA[pard];
            O[0] = mfma16(ap, bv0, O[0]);
            O[1] = mfma16(ap, bv1, O[1]);
            O[2] = mfma16(ap, bv2, O[2]);
            O[3] = mfma16(ap, bv3, O[3]);
        }
    }

#pragma unroll
    for (int r = 0; r < 4; r++) {
        float l = l_i[r];
#pragma unroll
        for (int o = 1; o < 16; o <<= 1) l += __shfl_xor(l, o, 64);
        float inv = 1.0f / l;
        int grow = i0 + rbase + r;
        u16* dst = head16 + (size_t)(b * Sx + grow) * 2048 + h * 64 + l15;
#pragma unroll
        for (int nt = 0; nt < 4; nt++) {
            float f = O[nt][r] * inv;
            u16 hh = f2bf(f);
            dst[16 * nt]        = hh;
            dst[1024 + 16 * nt] = f2bf(f - bf2f(hh));
        }
    }
}

// ---------------------------------------------------------------- launcher
extern "C" void kernel_launch(void* const* d_in, const int* in_sizes, int n_in,
                              void* d_out, int out_size, void* d_ws, size_t ws_size,
                              hipStream_t stream) {
    const float* x    = (const float*)d_in[0];
    const float* ln_g = (const float*)d_in[1];
    const float* ln_b = (const float*)d_in[2];
    const float* Wq   = (const float*)d_in[3];
    const float* bq   = (const float*)d_in[4];
    const float* Wk   = (const float*)d_in[5];
    const float* bk   = (const float*)d_in[6];
    const float* Wv   = (const float*)d_in[7];
    const float* bv   = (const float*)d_in[8];
    const float* Wp   = (const float*)d_in[9];
    const float* Wo   = (const float*)d_in[10];
    const float* bo   = (const float*)d_in[11];
    const float* ub   = (const float*)d_in[12];
    const float* vbias= (const float*)d_in[13];

    float* out = (float*)d_out;
    u16* base  = (u16*)d_ws;

    const int MROWS = 2 * Sx;                          // 4096
    u16* xn16   = base;                                // [4096][2048] hi|lo
    u16* head16 = base + 8u  * 1024 * 1024;            // [4096][2048] hi|lo
    u16* pe16   = base + 16u * 1024 * 1024;            // [2048][2048] hi|lo
    u16* qb16   = base + 20u * 1024 * 1024;            // [4096][1024]; k at +4M; p at +12M
    u16* kb16   = base + 24u * 1024 * 1024;
    u16* pp16   = base + 32u * 1024 * 1024;            // [2048][1024]
    u16* vT16   = base + 34u * 1024 * 1024;            // [2][16][64][64][32]
    u16* WT     = base + 38u * 1024 * 1024;            // 5 x [1024][2048]
    float* ukg  = (float*)(base + 48u * 1024 * 1024);
    float* vbg  = ukg + 2 * Hh * Sx;
    (void)kb16; (void)pp16;

    ln_kernel<<<MROWS, 256, 0, stream>>>(x, ln_g, ln_b, xn16);
    pe_kernel<<<Sx * 512 / 256, 256, 0, stream>>>(pe16);

    dim3 gw(32, 32, 5);
    wconv_kernel<<<gw, 256, 0, stream>>>(Wq, Wk, Wv, Wp, Wo, WT);

    // fused Q/K/V/P projections; V writes vT16 directly; u.k and vb.p fused in epilogue
    gemm128k<128><<<896, 256, 0, stream>>>(xn16, pe16, WT, bq, bk, bv,
                                           ub, vbias, ukg, vbg,
                                           qb16, vT16, nullptr, 0);

    flash_kernel<<<2 * Hh * 32, 256, 0, stream>>>(qb16, kb16, vT16, pp16, ukg, vbg, head16);

    gemm128k<64><<<dim3(8, 64), 256, 0, stream>>>(head16, nullptr, WT, bo, nullptr, nullptr,
                                                  nullptr, nullptr, nullptr, nullptr,
                                                  nullptr, nullptr, out, 1);
}